// Round 6
// baseline (100.856 us; speedup 1.0000x reference)
//
#include <hip/hip_runtime.h>

#define NMOL 16
#define NAT  512
#define NK   27

// Bit-exact float32 constants matching the numpy reference on host:
//   inv_cell diagonal = 1/20 correctly rounded = 0.05f (0x3D4CCCCD)
//   mask: dist<5.0 with correctly-rounded sqrt  <=>  ss < pred(25.0f) = 0x41C7FFFF
#define SSMAX 24.999998092651367f

__device__ __forceinline__ float wrap1(float v) {
    // proj = rn(v*0.05f); coords in [0,20) => proj<1 => woff=0, frac=proj
    // wrapped = rn(frac*20)
    return __fmul_rn(__fmul_rn(v, 0.05f), 20.0f);
}

// Candidate (unique possible) image per component + exact-mask squared distance
// test. Returns kk in 0..26 on hit, 31 on miss.
__device__ __forceinline__ int probe_code(float wx, float wy, float wz,
                                          float wjx, float wjy, float wjz,
                                          bool self) {
    float dx = __fsub_rn(wx, wjx);
    float dy = __fsub_rn(wy, wjy);
    float dz = __fsub_rn(wz, wjz);
    int ox = (dx > 15.0f) ? -1 : ((dx < -15.0f) ? 1 : 0);
    int oy = (dy > 15.0f) ? -1 : ((dy < -15.0f) ? 1 : 0);
    int oz = (dz > 15.0f) ? -1 : ((dz < -15.0f) ? 1 : 0);
    float ax = __fadd_rn(dx, 20.0f * (float)ox);
    float ay = __fadd_rn(dy, 20.0f * (float)oy);
    float az = __fadd_rn(dz, 20.0f * (float)oz);
    float ss = __fadd_rn(__fadd_rn(__fmul_rn(ax, ax), __fmul_rn(ay, ay)),
                         __fmul_rn(az, az));
    bool hit = (ss < SSMAX) && !self;
    return hit ? ((ox + 1) * 9 + (oy + 1) * 3 + (oz + 1)) : 31;
}

// ---------------- Pass A: count hits per (m,k,i) + per-block summaries ----------------
// 1024 blocks x 256 thr; block = (m, b) owns atoms [8b, 8b+8) of molecule m.
// Extra outputs vs R2: sub[(m*NK+k)*64 + b] = block's per-k total (plain store),
// blkmol[blk] = block's grand total (verified wave-0 shuffle reduce).
__global__ __launch_bounds__(256, 8) void pass_count(const float* __restrict__ coords,
                                                     int* __restrict__ cnt,
                                                     int* __restrict__ sub,
                                                     int* __restrict__ blkmol) {
    __shared__ float rr[NAT * 3];
    __shared__ int cur[2][4][NK];
    const int blk  = blockIdx.x;
    const int m    = blk >> 6;            // 64 blocks per molecule
    const int b    = blk & 63;
    const int g0   = b * 2;
    const int t    = threadIdx.x;
    const int w    = t >> 6;
    const int lane = t & 63;
    const int iA   = g0 * 4 + w;
    const int iB   = iA + 4;

    const float4* cm4 = reinterpret_cast<const float4*>(coords + (size_t)m * NAT * 3);
    float4* rr4 = reinterpret_cast<float4*>(rr);
    rr4[t] = cm4[t];                       // 384 float4 total
    if (t < 128) rr4[t + 256] = cm4[t + 256];
    if (t < 2 * 4 * NK) ((int*)cur)[t] = 0;
    __syncthreads();

    const float wAx = wrap1(rr[iA * 3 + 0]), wAy = wrap1(rr[iA * 3 + 1]), wAz = wrap1(rr[iA * 3 + 2]);
    const float wBx = wrap1(rr[iB * 3 + 0]), wBy = wrap1(rr[iB * 3 + 1]), wBz = wrap1(rr[iB * 3 + 2]);

    #pragma unroll
    for (int it = 0; it < NAT / 64; ++it) {
        const int j = it * 64 + lane;
        float wjx = wrap1(rr[j * 3 + 0]);
        float wjy = wrap1(rr[j * 3 + 1]);
        float wjz = wrap1(rr[j * 3 + 2]);
        int cA = probe_code(wAx, wAy, wAz, wjx, wjy, wjz, j == iA);
        int cB = probe_code(wBx, wBy, wBz, wjx, wjy, wjz, j == iB);
        if (cA != 31) atomicAdd(&cur[0][w][cA], 1);
        if (cB != 31) atomicAdd(&cur[1][w][cB], 1);
    }
    __syncthreads();
    if (t < 216) {
        int uu = t / 108, rem = t % 108, ww = rem / 27, k = rem % 27;
        int i = (g0 + uu) * 4 + ww;
        cnt[(m * NK + k) * NAT + i] = cur[uu][ww][k];
    }
    if (t < NK) {                          // per-k block subtotal
        int s = 0;
        #pragma unroll
        for (int uu = 0; uu < 2; ++uu)
            #pragma unroll
            for (int ww = 0; ww < 4; ++ww) s += cur[uu][ww][t];
        sub[(m * NK + t) * 64 + b] = s;
    }
    if (w == 0) {                          // block grand total (verified reduce)
        int s = 0;
        #pragma unroll
        for (int x = lane; x < 216; x += 64) s += ((int*)cur)[x];
        #pragma unroll
        for (int d = 1; d < 64; d <<= 1) s += __shfl_xor(s, d, 64);
        if (lane == 0) blkmol[blk] = s;
    }
}

// ---------------- Pass B: cursor build from summaries + ordered emit ----------------
// 1024 blocks x 256 thr, mirroring pass_count's block->atom mapping.
// cursor(k,i) = Sum_{m'<m} tot(m')            (blkmol wave reduces)
//             + Sum_{k'<k} ctot(m,k')         (serial over 27)
//             + Sum_{b'<b} sub(m,k,b')        (64-lane shfl scan per k)
//             + Sum_{a'<a in block} cnt(k,i') (8-value strip sums)
// == R2's global-scan cursor, reassociated over disjoint ranges.
__global__ __launch_bounds__(256, 8) void pass_emit(const float* __restrict__ coords,
                                                    const int* __restrict__ cnt,
                                                    const int* __restrict__ sub,
                                                    const int* __restrict__ blkmol,
                                                    float* __restrict__ out, int P) {
    __shared__ float rr[NAT * 3];
    __shared__ int cur[2][4][NK];
    __shared__ int strip[8][NK];
    __shared__ int ctot[NK], cpre[NK], kexcl[NK];
    __shared__ int tls[NMOL];
    const int blk  = blockIdx.x;
    const int m    = blk >> 6;
    const int b    = blk & 63;
    const int g0   = b * 2;
    const int t    = threadIdx.x;
    const int w    = t >> 6;
    const int lane = t & 63;

    // stage raw packed coords
    const float4* cm4 = reinterpret_cast<const float4*>(coords + (size_t)m * NAT * 3);
    float4* rr4 = reinterpret_cast<float4*>(rr);
    rr4[t] = cm4[t];
    if (t < 128) rr4[t + 256] = cm4[t + 256];

    // molecule totals: wave w reduces molecules w, w+4, w+8, w+12
    for (int mm = w; mm < NMOL; mm += 4) {
        int v = blkmol[mm * 64 + lane];
        #pragma unroll
        for (int d = 1; d < 64; d <<= 1) v += __shfl_xor(v, d, 64);
        if (lane == 0) tls[mm] = v;
    }
    // per-k: chunk total + prefix over blocks b' < b (one 64-lane scan per k)
    for (int k = w; k < NK; k += 4) {
        int v = sub[(m * NK + k) * 64 + lane];
        int incl = v;
        #pragma unroll
        for (int d = 1; d < 64; d <<= 1) {
            int u = __shfl_up(incl, d, 64);
            if (lane >= d) incl += u;
        }
        int tot   = __shfl(incl, 63, 64);
        int exclb = __shfl(incl - v, b, 64);
        if (lane == 0) { ctot[k] = tot; cpre[k] = exclb; }
    }
    // own 8-atom count strip
    if (t < 216) {
        int uu = t / 108, rem = t % 108, ww = rem / 27, k = rem % 27;
        int i = (g0 + uu) * 4 + ww;
        strip[uu * 4 + ww][k] = cnt[(m * NK + k) * NAT + i];
    }
    __syncthreads();
    if (t == 0) {
        int run = 0;
        for (int mm = 0; mm < m; ++mm) run += tls[mm];     // molecule base
        for (int k = 0; k < NK; ++k) { kexcl[k] = run; run += ctot[k]; }
    }
    __syncthreads();
    if (t < 216) {
        int uu = t / 108, rem = t % 108, ww = rem / 27, k = rem % 27;
        int a = uu * 4 + ww;
        int ip = 0;
        for (int a2 = 0; a2 < a; ++a2) ip += strip[a2][k];
        cur[uu][ww][k] = kexcl[k] + cpre[k] + ip;           // global cursor
    }
    __syncthreads();

    // ---- emit (verified R2 logic, byte-identical ordering semantics) ----
    const int iA = g0 * 4 + w, iB = iA + 4;
    const float rAx = rr[iA * 3 + 0], rAy = rr[iA * 3 + 1], rAz = rr[iA * 3 + 2];
    const float rBx = rr[iB * 3 + 0], rBy = rr[iB * 3 + 1], rBz = rr[iB * 3 + 2];
    const float wAx = wrap1(rAx), wAy = wrap1(rAy), wAz = wrap1(rAz);
    const float wBx = wrap1(rBx), wBy = wrap1(rBy), wBz = wrap1(rBz);
    const unsigned long long ltmask =
        (lane == 0) ? 0ull : (~0ull >> (64 - lane));

    #pragma unroll
    for (int it = 0; it < NAT / 64; ++it) {
        const int j = it * 64 + lane;
        const float rjx = rr[j * 3 + 0], rjy = rr[j * 3 + 1], rjz = rr[j * 3 + 2];
        const float wjx = wrap1(rjx), wjy = wrap1(rjy), wjz = wrap1(rjz);

        #pragma unroll
        for (int uu = 0; uu < 2; ++uu) {
            const int i  = (uu == 0) ? iA : iB;
            const float rx = (uu == 0) ? rAx : rBx;
            const float ry = (uu == 0) ? rAy : rBy;
            const float rz = (uu == 0) ? rAz : rBz;
            int code = (uu == 0)
                ? probe_code(wAx, wAy, wAz, wjx, wjy, wjz, j == iA)
                : probe_code(wBx, wBy, wBz, wjx, wjy, wjz, j == iB);
            bool hit = (code != 31);
            int kk = hit ? code : 0;

            // match-any over 5-bit kk among hitting lanes
            unsigned long long grp = __ballot(hit);
            #pragma unroll
            for (int bb = 0; bb < 5; ++bb) {
                unsigned long long bm = __ballot((kk >> bb) & 1);
                grp &= ((kk >> bb) & 1) ? bm : ~bm;
            }
            int leader = hit ? (__ffsll((unsigned long long)grp) - 1) : 0;
            int cntg   = __popcll(grp);
            int rank   = __popcll(grp & ltmask);

            int base = 0;
            if (hit && lane == leader)
                base = atomicAdd(&cur[uu][w][kk], cntg);   // ds_add_rtn cursor
            base = __shfl(base, leader, 64);               // broadcast from leader

            if (hit) {
                int p = base + rank;
                if (p < P) {
                    int ox = kk / 9;
                    int rem = kk - ox * 9;
                    int oy = rem / 3;
                    int oz = rem - oy * 3;
                    ox -= 1; oy -= 1; oz -= 1;
                    float cx = 20.0f * (float)ox;
                    float cy = 20.0f * (float)oy;
                    float cz = 20.0f * (float)oz;
                    float px = __fadd_rn(__fsub_rn(rx, rjx), cx);
                    float py = __fadd_rn(__fsub_rn(ry, rjy), cy);
                    float pz = __fadd_rn(__fsub_rn(rz, rjz), cz);
                    float ss = __fadd_rn(__fadd_rn(__fmul_rn(px, px), __fmul_rn(py, py)),
                                         __fmul_rn(pz, pz));
                    out[p]                 = __fsqrt_rn(ss);        // distflat2
                    out[P + p]             = (float)(m * NAT + i);  // pair_first
                    out[2 * P + p]         = (float)(m * NAT + j);  // pair_second
                    out[3 * P + 3 * p + 0] = px;                    // paircoord
                    out[3 * P + 3 * p + 1] = py;
                    out[3 * P + 3 * p + 2] = pz;
                    out[6 * P + 3 * p + 0] = (float)ox;             // offsets
                    out[6 * P + 3 * p + 1] = (float)oy;
                    out[6 * P + 3 * p + 2] = (float)oz;
                    out[9 * P + p]         = (float)kk;             // offset_index
                }
            }
        }
    }
}

extern "C" void kernel_launch(void* const* d_in, const int* in_sizes, int n_in,
                              void* d_out, int out_size, void* d_ws, size_t ws_size,
                              hipStream_t stream) {
    (void)in_sizes; (void)n_in; (void)ws_size;
    const float* coords = (const float*)d_in[0];
    int* cnt    = (int*)d_ws;                  // 16*27*512 ints
    int* sub    = cnt + NMOL * NK * NAT;       // 16*27*64 ints
    int* blkmol = sub + NMOL * NK * 64;        // 1024 ints
    float* out  = (float*)d_out;
    const int P = out_size / 10;

    hipLaunchKernelGGL(pass_count, dim3(NMOL * NAT / 8), dim3(256), 0, stream,
                       coords, cnt, sub, blkmol);
    hipLaunchKernelGGL(pass_emit, dim3(NMOL * NAT / 8), dim3(256), 0, stream,
                       coords, cnt, sub, blkmol, out, P);
}